// Round 5
// baseline (2263.369 us; speedup 1.0000x reference)
//
#include <hip/hip_runtime.h>
#include <hip/hip_bf16.h>

#define IN_CH 256
#define OUT_CH 64
#define RPB   128          // rows per fine bucket (b = r >> 7)
#define RSH   7
#define NFMAX 1024         // max fine buckets (n <= 131072)
#define CHUNK 6144         // edges per fine_scatter block (24 per thread)

// ---- bf16 helpers ----
__device__ __forceinline__ unsigned short f2bf(float f) {   // manual RNE (prep paths)
    unsigned u = __float_as_uint(f);
    u += 0x7fff + ((u >> 16) & 1);
    return (unsigned short)(u >> 16);
}
__device__ __forceinline__ unsigned short f2bf_hw(float f) { // HW cvt (pairs into v_cvt_pk_bf16_f32)
    __hip_bfloat16 h = __float2bfloat16(f);
    union { __hip_bfloat16 b; unsigned short u; } c;
    c.b = h;
    return c.u;
}
__device__ __forceinline__ float bf2f(unsigned short h) {
    return __uint_as_float((unsigned)h << 16);
}

using bfrag = __attribute__((ext_vector_type(8))) short;   // 8 bf16 (4 VGPRs)
using ffrag = __attribute__((ext_vector_type(4))) float;   // 4 fp32 acc
using f32x4 = __attribute__((ext_vector_type(4))) float;   // vector type for NT loads

// ---------------------------------------------------------------------------
// W pre-convert: fragment-major bf16 Wf (32 KB), written once.
// ---------------------------------------------------------------------------
__global__ __launch_bounds__(256) void wprep_kernel(
    const float* __restrict__ W, unsigned short* __restrict__ Wf)
{
    int i = blockIdx.x * 256 + threadIdx.x;   // 64 blocks x 256 = 16384
    int k  = i >> 6;
    int c  = i & 63;
    int ks = k >> 5;
    int kq = (k >> 3) & 3;
    int j  = k & 7;
    int nt = c >> 4;
    int lc = c & 15;
    Wf[(((ks * 4 + nt) * 64) + kq * 16 + lc) * 8 + j] = f2bf(W[i]);
}

// ---------------------------------------------------------------------------
// MFMA dense transform v4 (unchanged): 16 rows/wave, full-row NT prefetch.
// ---------------------------------------------------------------------------
__global__ __launch_bounds__(256) void gemm_mfma_kernel(
    const float* __restrict__ feat, const unsigned short* __restrict__ Wf,
    const float* __restrict__ bias, unsigned short* __restrict__ out, int n)
{
    const int wv   = threadIdx.x >> 6;
    const int lane = threadIdx.x & 63;
    const int quad = lane >> 4;
    const int lc   = lane & 15;

    const int rbase = blockIdx.x * 64 + wv * 16;
    const int lrow  = min(rbase + lc, n - 1);
    const f32x4* frow = (const f32x4*)(feat + (size_t)lrow * IN_CH);

    f32x4 a[16];
#pragma unroll
    for (int i = 0; i < 16; ++i) {
        int ks = i >> 1;
        int j  = i & 1;
        a[i] = __builtin_nontemporal_load(frow + ks * 8 + quad * 2 + j);
    }

    ffrag acc[4];
#pragma unroll
    for (int nt = 0; nt < 4; ++nt)
#pragma unroll
        for (int r = 0; r < 4; ++r) acc[nt][r] = 0.f;

#pragma unroll
    for (int ks = 0; ks < 8; ++ks) {
        f32x4 a0 = a[ks * 2 + 0];
        f32x4 a1 = a[ks * 2 + 1];
        bfrag af;
        af[0] = (short)f2bf_hw(a0[0]); af[1] = (short)f2bf_hw(a0[1]);
        af[2] = (short)f2bf_hw(a0[2]); af[3] = (short)f2bf_hw(a0[3]);
        af[4] = (short)f2bf_hw(a1[0]); af[5] = (short)f2bf_hw(a1[1]);
        af[6] = (short)f2bf_hw(a1[2]); af[7] = (short)f2bf_hw(a1[3]);
#pragma unroll
        for (int nt = 0; nt < 4; ++nt) {
            bfrag bf = *(const bfrag*)&Wf[(((ks * 4 + nt) * 64) + lane) * 8];
            acc[nt] = __builtin_amdgcn_mfma_f32_16x16x32_bf16(af, bf, acc[nt], 0, 0, 0);
        }
    }

#pragma unroll
    for (int nt = 0; nt < 4; ++nt) {
        float bv = bias[nt * 16 + lc];
#pragma unroll
        for (int r = 0; r < 4; ++r) {
            int orow = rbase + quad * 4 + r;
            if (orow < n) {
                float v = fmaxf(acc[nt][r] + bv, 0.f);
                out[(size_t)orow * OUT_CH + nt * 16 + lc] = f2bf_hw(v);
            }
        }
    }
}

// ---------------------------------------------------------------------------
// Edge bucketing (counting sort to fine buckets only — no per-row sort).
// Record: int2 { x = col | (row_in_bucket << 20), y = bits(val) }.
// ---------------------------------------------------------------------------
__global__ __launch_bounds__(256) void fine_count_kernel(
    const int* __restrict__ rows, int* __restrict__ fineCnt,
    int nEdges, int nfine)
{
    __shared__ int h[NFMAX];
    const int t = threadIdx.x;
    for (int i = t; i < nfine; i += 256) h[i] = 0;
    __syncthreads();
    const int stride = gridDim.x * 256;
    for (int e = blockIdx.x * 256 + t; e < nEdges; e += stride)
        atomicAdd(&h[__builtin_nontemporal_load(rows + e) >> RSH], 1);
    __syncthreads();
    for (int i = t; i < nfine; i += 256) {
        int v = h[i];
        if (v) atomicAdd(&fineCnt[i], v);
    }
}

__global__ __launch_bounds__(256) void fine_scan_kernel(
    const int* __restrict__ fineCnt, int* __restrict__ fineBase,
    int* __restrict__ flushCursor, int nfine, int E)
{
    __shared__ int tmp[256];
    const int t = threadIdx.x;
    int v[4];
    int s = 0;
#pragma unroll
    for (int j = 0; j < 4; ++j) {
        int i = t * 4 + j;
        v[j] = (i < nfine) ? fineCnt[i] : 0;
        s += v[j];
    }
    tmp[t] = s;
    __syncthreads();
    for (int off = 1; off < 256; off <<= 1) {
        int x = (t >= off) ? tmp[t - off] : 0;
        __syncthreads();
        tmp[t] += x;
        __syncthreads();
    }
    int excl = tmp[t] - s;
#pragma unroll
    for (int j = 0; j < 4; ++j) {
        int i = t * 4 + j;
        if (i < nfine) { fineBase[i] = excl; flushCursor[i] = excl; }
        excl += v[j];
    }
    if (t == 0) fineBase[nfine] = E;
}

__global__ __launch_bounds__(256) void fine_scatter_kernel(
    const int* __restrict__ rows, const int* __restrict__ cols,
    const float* __restrict__ vals, int* __restrict__ flushCursor,
    int2* __restrict__ ebcv, int nEdges, int nfine)
{
    __shared__ int hist[NFMAX];
    __shared__ int lofs[NFMAX];
    __shared__ int gpos[NFMAX];
    __shared__ int cur[NFMAX];
    __shared__ int scanTmp[256];
    __shared__ int   sr[CHUNK];
    __shared__ int   sc[CHUNK];
    __shared__ float sv[CHUNK];

    const int t  = threadIdx.x;
    const int e0 = blockIdx.x * CHUNK;
    const int cnt_in = min(CHUNK, nEdges - e0);

    for (int i = t; i < nfine; i += 256) hist[i] = 0;
    __syncthreads();

    int   lr[CHUNK / 256];
    int   lc[CHUNK / 256];
    float lv[CHUNK / 256];
#pragma unroll
    for (int j = 0; j < CHUNK / 256; ++j) {
        int i = j * 256 + t;
        if (i < cnt_in) {
            lr[j] = __builtin_nontemporal_load(rows + e0 + i);
            lc[j] = __builtin_nontemporal_load(cols + e0 + i);
            lv[j] = __builtin_nontemporal_load(vals + e0 + i);
            atomicAdd(&hist[lr[j] >> RSH], 1);
        } else {
            lr[j] = -1;
        }
    }
    __syncthreads();

    // exclusive scan of hist, 4 bins per thread (nfine <= 1024)
    int v4[4];
    int s4 = 0;
#pragma unroll
    for (int j = 0; j < 4; ++j) {
        int i = t * 4 + j;
        v4[j] = (i < nfine) ? hist[i] : 0;
        s4 += v4[j];
    }
    scanTmp[t] = s4;
    __syncthreads();
    for (int off = 1; off < 256; off <<= 1) {
        int x = (t >= off) ? scanTmp[t - off] : 0;
        __syncthreads();
        scanTmp[t] += x;
        __syncthreads();
    }
    int excl = scanTmp[t] - s4;
#pragma unroll
    for (int j = 0; j < 4; ++j) {
        int i = t * 4 + j;
        if (i < nfine) lofs[i] = excl;
        excl += v4[j];
    }
    __syncthreads();

    // global segment reservations + staging cursors
    for (int i = t; i < nfine; i += 256) {
        int h = hist[i];
        gpos[i] = h ? atomicAdd(&flushCursor[i], h) : 0;
        cur[i]  = lofs[i];
    }
    __syncthreads();

    // place edges into LDS staging grouped by bucket
#pragma unroll
    for (int j = 0; j < CHUNK / 256; ++j) {
        if (lr[j] >= 0) {
            int bk = lr[j] >> RSH;
            int p  = atomicAdd(&cur[bk], 1);
            sr[p] = lr[j];
            sc[p] = lc[j];
            sv[p] = lv[j];
        }
    }
    __syncthreads();

    // flush: consecutive staging indices -> contiguous global segments
    for (int i = t; i < cnt_in; i += 256) {
        int bk = sr[i] >> RSH;
        int rl = sr[i] & (RPB - 1);
        int p  = gpos[bk] + (i - lofs[bk]);
        ebcv[p] = make_int2(sc[i] | (rl << 20), __float_as_int(sv[i]));
    }
}

// ---------------------------------------------------------------------------
// SpMM hop v3: one block per fine bucket, dst tile accumulated in LDS fp32
// via ds_add_f32 (bank = lane&31, 2-way same-bank = free). One edge per
// wave (lane = channel, 2 B gather -> exactly the 128 B src row), 8 edges
// in flight per wave. Consumes bucket-grouped UNSORTED edges -> the whole
// per-row sort (bucket_sort + spack) is deleted.
// ---------------------------------------------------------------------------
template<bool DST_F32>
__global__ __launch_bounds__(256) void spmm_bucket_kernel(
    const int2* __restrict__ ebcv, const int* __restrict__ fineBase,
    const unsigned short* __restrict__ src, void* __restrict__ dstv, int n)
{
    __shared__ float acc[RPB * OUT_CH];   // 32 KB
    const int t    = threadIdx.x;
    const int wv   = t >> 6;
    const int lane = t & 63;

    for (int i = t; i < RPB * OUT_CH; i += 256) acc[i] = 0.f;
    __syncthreads();

    const int bkt = blockIdx.x;
    const int lo  = fineBase[bkt];
    const int hi  = fineBase[bkt + 1];

    for (int b = lo + wv * 8; b < hi; b += 32) {   // 4 waves x 8-deep
        int2 p[8];
#pragma unroll
        for (int j = 0; j < 8; ++j)
            p[j] = ebcv[min(b + j, hi - 1)];
        unsigned short sw[8];
#pragma unroll
        for (int j = 0; j < 8; ++j) {
            int c = p[j].x & 0xFFFFF;
            sw[j] = src[((size_t)c << 6) + lane];
        }
#pragma unroll
        for (int j = 0; j < 8; ++j) {
            if (b + j < hi) {                       // wave-uniform branch
                int   rl = p[j].x >> 20;
                float v  = __int_as_float(p[j].y);
                atomicAdd(&acc[rl * OUT_CH + lane], v * bf2f(sw[j]));
            }
        }
    }
    __syncthreads();

    const int r0 = bkt * RPB;
    if constexpr (DST_F32) {
        float* out = (float*)dstv;
        for (int i = t; i < RPB * 16; i += 256) {
            int row = i >> 4, seg = i & 15;
            if (r0 + row < n)
                *(float4*)(out + ((size_t)(r0 + row) << 6) + seg * 4) =
                    *(float4*)&acc[row * OUT_CH + seg * 4];
        }
    } else {
        unsigned short* out = (unsigned short*)dstv;
        for (int i = t; i < RPB * 16; i += 256) {
            int row = i >> 4, seg = i & 15;
            if (r0 + row < n) {
                ushort4 o;
                o.x = f2bf_hw(acc[row * OUT_CH + seg * 4 + 0]);
                o.y = f2bf_hw(acc[row * OUT_CH + seg * 4 + 1]);
                o.z = f2bf_hw(acc[row * OUT_CH + seg * 4 + 2]);
                o.w = f2bf_hw(acc[row * OUT_CH + seg * 4 + 3]);
                *(ushort4*)(out + ((size_t)(r0 + row) << 6) + seg * 4) = o;
            }
        }
    }
}

// ---------------------------------------------------------------------------
extern "C" void kernel_launch(void* const* d_in, const int* in_sizes, int n_in,
                              void* d_out, int out_size, void* d_ws, size_t ws_size,
                              hipStream_t stream)
{
    const int*   adj  = (const int*)d_in[0];    // [2, E] int32
    const float* vals = (const float*)d_in[1];  // [E]
    const float* feat = (const float*)d_in[2];  // [N, 256]
    const float* W    = (const float*)d_in[3];  // [256, 64]
    const float* bias = (const float*)d_in[4];  // [1, 64]

    const int E = in_sizes[1];
    const int n = in_sizes[2] / IN_CH;
    const int* rows = adj;       // destination rows
    const int* cols = adj + E;   // gather sources

    const int nfine = (n + RPB - 1) >> RSH;   // fine buckets of 128 rows

    // ---- workspace layout (256 B aligned regions; no aliasing) ----
    char* ws = (char*)d_ws;
    size_t off = 0;
    auto alloc = [&](size_t bytes) {
        void* p = ws + off;
        off += (bytes + 255) & ~(size_t)255;
        return p;
    };
    unsigned short* B0 = (unsigned short*)alloc((size_t)n * OUT_CH * sizeof(unsigned short));
    unsigned short* B1 = (unsigned short*)alloc((size_t)n * OUT_CH * sizeof(unsigned short));
    int2*  ebcv        = (int2*) alloc((size_t)E * sizeof(int2));
    int*   fineCnt     = (int*)  alloc(NFMAX * sizeof(int));
    int*   fineBase    = (int*)  alloc((NFMAX + 1) * sizeof(int));
    int*   flushCursor = (int*)  alloc(NFMAX * sizeof(int));
    unsigned short* Wf = (unsigned short*)alloc((size_t)IN_CH * OUT_CH * sizeof(unsigned short));

    float* out = (float*)d_out;

    // ---- W pre-convert (independent, tiny) ----
    wprep_kernel<<<(IN_CH * OUT_CH) / 256, 256, 0, stream>>>(W, Wf);

    // ---- bucket edges (counting sort to 128-row buckets) ----
    hipMemsetAsync(fineCnt, 0, (size_t)nfine * sizeof(int), stream);
    fine_count_kernel<<<256, 256, 0, stream>>>(rows, fineCnt, E, nfine);
    fine_scan_kernel<<<1, 256, 0, stream>>>(fineCnt, fineBase, flushCursor,
                                            nfine, E);
    fine_scatter_kernel<<<(E + CHUNK - 1) / CHUNK, 256, 0, stream>>>(
        rows, cols, vals, flushCursor, ebcv, E, nfine);

    // ---- dense transform (MFMA, bf16 output, full-row prefetch) ----
    gemm_mfma_kernel<<<(n + 63) / 64, 256, 0, stream>>>(feat, Wf, bias, B0, n);

    // ---- 3 SpMM hops (LDS-accumulated): B0 -> B1 -> B0 -> out(fp32) ----
    spmm_bucket_kernel<false><<<nfine, 256, 0, stream>>>(ebcv, fineBase, B0, B1, n);
    spmm_bucket_kernel<false><<<nfine, 256, 0, stream>>>(ebcv, fineBase, B1, B0, n);
    spmm_bucket_kernel<true ><<<nfine, 256, 0, stream>>>(ebcv, fineBase, B0, out, n);
}

// Round 6
// 376.451 us; speedup vs baseline: 6.0124x; 6.0124x over previous
//
#include <hip/hip_runtime.h>
#include <hip/hip_bf16.h>

#define IN_CH 256
#define OUT_CH 64
#define NFMAX 512          // max fine buckets (n <= 131072)
#define RPB 256            // rows per fine bucket (b = r >> 8)
#define CHUNK 6144         // edges per fine_scatter block (24 per thread)
#define CAP 8192           // staged edges per bucket_sort window (64 KB LDS)

// ---- bf16 helpers ----
__device__ __forceinline__ unsigned short f2bf(float f) {   // manual RNE (prep paths)
    unsigned u = __float_as_uint(f);
    u += 0x7fff + ((u >> 16) & 1);
    return (unsigned short)(u >> 16);
}
__device__ __forceinline__ unsigned short f2bf_hw(float f) { // HW cvt (pairs into v_cvt_pk_bf16_f32)
    __hip_bfloat16 h = __float2bfloat16(f);
    union { __hip_bfloat16 b; unsigned short u; } c;
    c.b = h;
    return c.u;
}
__device__ __forceinline__ float bf2f(unsigned short h) {
    return __uint_as_float((unsigned)h << 16);
}

using bfrag = __attribute__((ext_vector_type(8))) short;   // 8 bf16 (4 VGPRs)
using ffrag = __attribute__((ext_vector_type(4))) float;   // 4 fp32 acc
using f32x4 = __attribute__((ext_vector_type(4))) float;   // vector type for NT loads

// ---------------------------------------------------------------------------
// W pre-convert: fragment-major bf16 Wf (32 KB), written once.
// ---------------------------------------------------------------------------
__global__ __launch_bounds__(256) void wprep_kernel(
    const float* __restrict__ W, unsigned short* __restrict__ Wf)
{
    int i = blockIdx.x * 256 + threadIdx.x;   // 64 blocks x 256 = 16384
    int k  = i >> 6;
    int c  = i & 63;
    int ks = k >> 5;
    int kq = (k >> 3) & 3;
    int j  = k & 7;
    int nt = c >> 4;
    int lc = c & 15;
    Wf[(((ks * 4 + nt) * 64) + kq * 16 + lc) * 8 + j] = f2bf(W[i]);
}

// ---------------------------------------------------------------------------
// MFMA dense transform v4: 16 rows/wave, FULL row prefetch (16 x 16 B NT
// loads in flight before any convert/MFMA). NT keeps Wf resident in L1.
// ---------------------------------------------------------------------------
__global__ __launch_bounds__(256) void gemm_mfma_kernel(
    const float* __restrict__ feat, const unsigned short* __restrict__ Wf,
    const float* __restrict__ bias, unsigned short* __restrict__ out, int n)
{
    const int wv   = threadIdx.x >> 6;
    const int lane = threadIdx.x & 63;
    const int quad = lane >> 4;
    const int lc   = lane & 15;

    const int rbase = blockIdx.x * 64 + wv * 16;
    const int lrow  = min(rbase + lc, n - 1);
    const f32x4* frow = (const f32x4*)(feat + (size_t)lrow * IN_CH);

    f32x4 a[16];
#pragma unroll
    for (int i = 0; i < 16; ++i) {
        int ks = i >> 1;
        int j  = i & 1;
        a[i] = __builtin_nontemporal_load(frow + ks * 8 + quad * 2 + j);
    }

    ffrag acc[4];
#pragma unroll
    for (int nt = 0; nt < 4; ++nt)
#pragma unroll
        for (int r = 0; r < 4; ++r) acc[nt][r] = 0.f;

#pragma unroll
    for (int ks = 0; ks < 8; ++ks) {
        f32x4 a0 = a[ks * 2 + 0];
        f32x4 a1 = a[ks * 2 + 1];
        bfrag af;
        af[0] = (short)f2bf_hw(a0[0]); af[1] = (short)f2bf_hw(a0[1]);
        af[2] = (short)f2bf_hw(a0[2]); af[3] = (short)f2bf_hw(a0[3]);
        af[4] = (short)f2bf_hw(a1[0]); af[5] = (short)f2bf_hw(a1[1]);
        af[6] = (short)f2bf_hw(a1[2]); af[7] = (short)f2bf_hw(a1[3]);
#pragma unroll
        for (int nt = 0; nt < 4; ++nt) {
            bfrag bf = *(const bfrag*)&Wf[(((ks * 4 + nt) * 64) + lane) * 8];
            acc[nt] = __builtin_amdgcn_mfma_f32_16x16x32_bf16(af, bf, acc[nt], 0, 0, 0);
        }
    }

#pragma unroll
    for (int nt = 0; nt < 4; ++nt) {
        float bv = bias[nt * 16 + lc];
#pragma unroll
        for (int r = 0; r < 4; ++r) {
            int orow = rbase + quad * 4 + r;
            if (orow < n) {
                float v = fmaxf(acc[nt][r] + bv, 0.f);
                out[(size_t)orow * OUT_CH + nt * 16 + lc] = f2bf_hw(v);
            }
        }
    }
}

// ---------------------------------------------------------------------------
// CSR build v3.1: LDS-staged counting sort; all global writes contiguous.
// Edge records split SoA: ebcv (c,v int2) + ebr (in-bucket row, u8).
// ---------------------------------------------------------------------------
__global__ __launch_bounds__(256) void fine_count_kernel(
    const int* __restrict__ rows, int* __restrict__ fineCnt,
    int nEdges, int nfine)
{
    __shared__ int h[NFMAX];
    const int t = threadIdx.x;
    for (int i = t; i < nfine; i += 256) h[i] = 0;
    __syncthreads();
    const int stride = gridDim.x * 256;
    for (int e = blockIdx.x * 256 + t; e < nEdges; e += stride)
        atomicAdd(&h[__builtin_nontemporal_load(rows + e) >> 8], 1);
    __syncthreads();
    for (int i = t; i < nfine; i += 256) {
        int v = h[i];
        if (v) atomicAdd(&fineCnt[i], v);
    }
}

__global__ __launch_bounds__(256) void fine_scan_kernel(
    const int* __restrict__ fineCnt, int* __restrict__ fineBase,
    int* __restrict__ flushCursor, int* __restrict__ rowptr,
    int n, int nfine, int E)
{
    __shared__ int tmp[256];
    const int t = threadIdx.x;
    int a = (2 * t     < nfine) ? fineCnt[2 * t]     : 0;
    int b = (2 * t + 1 < nfine) ? fineCnt[2 * t + 1] : 0;
    tmp[t] = a + b;
    __syncthreads();
    for (int off = 1; off < 256; off <<= 1) {
        int x = (t >= off) ? tmp[t - off] : 0;
        __syncthreads();
        tmp[t] += x;
        __syncthreads();
    }
    int excl = tmp[t] - (a + b);
    if (2 * t < nfine)     { fineBase[2 * t]     = excl;     flushCursor[2 * t]     = excl;     }
    if (2 * t + 1 < nfine) { fineBase[2 * t + 1] = excl + a; flushCursor[2 * t + 1] = excl + a; }
    if (t == 0) { fineBase[nfine] = E; rowptr[n] = E; }
}

__global__ __launch_bounds__(256) void fine_scatter_kernel(
    const int* __restrict__ rows, const int* __restrict__ cols,
    const float* __restrict__ vals, int* __restrict__ flushCursor,
    int2* __restrict__ ebcv, unsigned char* __restrict__ ebr,
    int nEdges, int nfine)
{
    __shared__ int hist[NFMAX];
    __shared__ int lofs[NFMAX];
    __shared__ int gpos[NFMAX];
    __shared__ int cur[NFMAX];
    __shared__ int scanTmp[256];
    __shared__ int   sr[CHUNK];
    __shared__ int   sc[CHUNK];
    __shared__ float sv[CHUNK];

    const int t  = threadIdx.x;
    const int e0 = blockIdx.x * CHUNK;
    const int cnt_in = min(CHUNK, nEdges - e0);

    for (int i = t; i < nfine; i += 256) hist[i] = 0;
    __syncthreads();

    int   lr[CHUNK / 256];
    int   lc[CHUNK / 256];
    float lv[CHUNK / 256];
#pragma unroll
    for (int j = 0; j < CHUNK / 256; ++j) {
        int i = j * 256 + t;
        if (i < cnt_in) {
            lr[j] = __builtin_nontemporal_load(rows + e0 + i);
            lc[j] = __builtin_nontemporal_load(cols + e0 + i);
            lv[j] = __builtin_nontemporal_load(vals + e0 + i);
            atomicAdd(&hist[lr[j] >> 8], 1);
        } else {
            lr[j] = -1;
        }
    }
    __syncthreads();

    int a  = (2 * t     < nfine) ? hist[2 * t]     : 0;
    int b2 = (2 * t + 1 < nfine) ? hist[2 * t + 1] : 0;
    scanTmp[t] = a + b2;
    __syncthreads();
    for (int off = 1; off < 256; off <<= 1) {
        int x = (t >= off) ? scanTmp[t - off] : 0;
        __syncthreads();
        scanTmp[t] += x;
        __syncthreads();
    }
    int excl = scanTmp[t] - (a + b2);
    if (2 * t < nfine)     lofs[2 * t]     = excl;
    if (2 * t + 1 < nfine) lofs[2 * t + 1] = excl + a;
    __syncthreads();

    for (int i = t; i < nfine; i += 256) {
        int h = hist[i];
        gpos[i] = h ? atomicAdd(&flushCursor[i], h) : 0;
        cur[i]  = lofs[i];
    }
    __syncthreads();

#pragma unroll
    for (int j = 0; j < CHUNK / 256; ++j) {
        if (lr[j] >= 0) {
            int bk = lr[j] >> 8;
            int p  = atomicAdd(&cur[bk], 1);
            sr[p] = lr[j];
            sc[p] = lc[j];
            sv[p] = lv[j];
        }
    }
    __syncthreads();

    for (int i = t; i < cnt_in; i += 256) {
        int bk = sr[i] >> 8;
        int p  = gpos[bk] + (i - lofs[bk]);
        ebcv[p] = make_int2(sc[i], __float_as_int(sv[i]));
        ebr[p]  = (unsigned char)(sr[i] & 255);
    }
}

__global__ __launch_bounds__(256) void bucket_sort_kernel(
    const int2* __restrict__ ebcv, const unsigned char* __restrict__ ebr,
    const int* __restrict__ fineBase,
    int2* __restrict__ spack, int* __restrict__ rowptr, int n)
{
    __shared__ int  rowCnt[RPB];
    __shared__ int  rowStart[RPB + 1];
    __shared__ int  scanTmp[RPB];
    __shared__ int  winEnd;
    __shared__ int2 st[CAP];            // 64 KB staging

    const int bkt = blockIdx.x;
    const int t   = threadIdx.x;
    const int lo  = fineBase[bkt];
    const int hi  = fineBase[bkt + 1];
    const int r0  = bkt << 8;

    rowCnt[t] = 0;
    __syncthreads();
    for (int e = lo + t; e < hi; e += 256)
        atomicAdd(&rowCnt[ebr[e]], 1);
    __syncthreads();

    int v = rowCnt[t];
    scanTmp[t] = v;
    __syncthreads();
    for (int off = 1; off < 256; off <<= 1) {
        int x = (t >= off) ? scanTmp[t - off] : 0;
        __syncthreads();
        scanTmp[t] += x;
        __syncthreads();
    }
    rowStart[t + 1] = scanTmp[t];
    if (t == 0) rowStart[0] = 0;
    __syncthreads();

    if (r0 + t < n) rowptr[r0 + t] = lo + rowStart[t];

    int rs = 0;
    while (rs < RPB) {
        if (t == 0) {
            int base = rowStart[rs];
            if (rowStart[rs + 1] - base > CAP) {
                winEnd = -(rs + 1);
            } else {
                int re = rs;
                while (re < RPB && rowStart[re + 1] - base <= CAP) ++re;
                winEnd = re;
            }
        }
        __syncthreads();
        int  re     = winEnd;
        bool direct = false;
        if (re < 0) { re = -re; direct = true; }
        const int base = rowStart[rs];
        const int cnt  = rowStart[re] - base;

        if (t >= rs && t < re) rowCnt[t] = rowStart[t] - base;
        __syncthreads();

        if (!direct) {
            for (int e = lo + t; e < hi; e += 256) {
                int rl = ebr[e];
                if (rl >= rs && rl < re) {
                    int p = atomicAdd(&rowCnt[rl], 1);
                    st[p] = ebcv[e];
                }
            }
            __syncthreads();
            for (int i = t; i < cnt; i += 256)
                spack[lo + base + i] = st[i];
        } else {
            for (int e = lo + t; e < hi; e += 256) {
                int rl = ebr[e];
                if (rl == rs) {
                    int p = atomicAdd(&rowCnt[rs], 1);
                    spack[lo + base + p] = ebcv[e];
                }
            }
        }
        __syncthreads();
        rs = re;
    }
}

// ---------------------------------------------------------------------------
// CSR SpMM hop v2.1: one row per quarter-wave (4 rows/wave, 16 rows/block),
// 8 edges in flight per quarter-wave (was 4) -> halves serialized-latency
// trips at avg degree 16.
// ---------------------------------------------------------------------------
template<bool DST_F32>
__global__ __launch_bounds__(256) void spmm_csr_kernel(
    const int* __restrict__ rowptr, const int2* __restrict__ spack,
    const unsigned short* __restrict__ src, void* __restrict__ dstv, int n)
{
    const int wid  = threadIdx.x >> 6;
    const int lane = threadIdx.x & 63;
    const int sub  = lane >> 4;
    const int ch   = (lane & 15) * 4;
    const int row  = blockIdx.x * 16 + wid * 4 + sub;
    const bool valid = row < n;

    int beg = 0, end = 0;
    if (valid) { beg = rowptr[row]; end = rowptr[row + 1]; }

    float4 acc = make_float4(0.f, 0.f, 0.f, 0.f);

    for (int b = beg; b < end; b += 8) {
        int2  p[8];
        float v[8];
#pragma unroll
        for (int j = 0; j < 8; ++j) {
            int e = b + j;
            p[j] = spack[min(e, end - 1)];
            v[j] = (e < end) ? __int_as_float(p[j].y) : 0.f;
        }
        ushort4 s[8];
#pragma unroll
        for (int j = 0; j < 8; ++j)
            s[j] = *(const ushort4*)(src + ((size_t)p[j].x << 6) + ch);
#pragma unroll
        for (int j = 0; j < 8; ++j) {
            acc.x = fmaf(v[j], bf2f(s[j].x), acc.x);
            acc.y = fmaf(v[j], bf2f(s[j].y), acc.y);
            acc.z = fmaf(v[j], bf2f(s[j].z), acc.z);
            acc.w = fmaf(v[j], bf2f(s[j].w), acc.w);
        }
    }

    if (valid) {
        if constexpr (DST_F32) {
            *(float4*)((float*)dstv + ((size_t)row << 6) + ch) = acc;
        } else {
            ushort4 o;
            o.x = f2bf_hw(acc.x);
            o.y = f2bf_hw(acc.y);
            o.z = f2bf_hw(acc.z);
            o.w = f2bf_hw(acc.w);
            *(ushort4*)((unsigned short*)dstv + ((size_t)row << 6) + ch) = o;
        }
    }
}

// ---------------------------------------------------------------------------
extern "C" void kernel_launch(void* const* d_in, const int* in_sizes, int n_in,
                              void* d_out, int out_size, void* d_ws, size_t ws_size,
                              hipStream_t stream)
{
    const int*   adj  = (const int*)d_in[0];    // [2, E] int32
    const float* vals = (const float*)d_in[1];  // [E]
    const float* feat = (const float*)d_in[2];  // [N, 256]
    const float* W    = (const float*)d_in[3];  // [256, 64]
    const float* bias = (const float*)d_in[4];  // [1, 64]

    const int E = in_sizes[1];
    const int n = in_sizes[2] / IN_CH;
    const int* rows = adj;       // destination rows
    const int* cols = adj + E;   // gather sources

    const int nfine = (n + RPB - 1) >> 8;   // fine buckets of 256 rows

    // ---- workspace layout (256 B aligned regions) ----
    char* ws = (char*)d_ws;
    size_t off = 0;
    auto alloc = [&](size_t bytes) {
        void* p = ws + off;
        off += (bytes + 255) & ~(size_t)255;
        return p;
    };
    unsigned short* B0 = (unsigned short*)alloc((size_t)n * OUT_CH * sizeof(unsigned short));
    unsigned short* B1 = (unsigned short*)alloc((size_t)n * OUT_CH * sizeof(unsigned short));
    int*   rowptr      = (int*)  alloc((size_t)(n + 1) * sizeof(int));
    int2*  spack       = (int2*) alloc((size_t)E * sizeof(int2));
    int*   fineCnt     = (int*)  alloc(NFMAX * sizeof(int));
    int*   fineBase    = (int*)  alloc((NFMAX + 1) * sizeof(int));
    int*   flushCursor = (int*)  alloc(NFMAX * sizeof(int));
    unsigned short* Wf = (unsigned short*)alloc((size_t)IN_CH * OUT_CH * sizeof(unsigned short));

    // packed edge records alias B0+B1 (dead until gemm, stream-ordered after
    // bucket_sort): E*8 + E*1 = 14.4 MB <= 25.6 MB.
    int2*          ebcv = (int2*)B0;
    unsigned char* ebr  = (unsigned char*)(ebcv + E);

    float* out = (float*)d_out;

    // ---- W pre-convert (independent, tiny) ----
    wprep_kernel<<<(IN_CH * OUT_CH) / 256, 256, 0, stream>>>(W, Wf);

    // ---- build CSR (LDS-staged counting sort) ----
    hipMemsetAsync(fineCnt, 0, (size_t)nfine * sizeof(int), stream);
    fine_count_kernel<<<256, 256, 0, stream>>>(rows, fineCnt, E, nfine);
    fine_scan_kernel<<<1, 256, 0, stream>>>(fineCnt, fineBase, flushCursor,
                                            rowptr, n, nfine, E);
    fine_scatter_kernel<<<(E + CHUNK - 1) / CHUNK, 256, 0, stream>>>(
        rows, cols, vals, flushCursor, ebcv, ebr, E, nfine);
    bucket_sort_kernel<<<nfine, 256, 0, stream>>>(ebcv, ebr, fineBase,
                                                  spack, rowptr, n);

    // ---- dense transform (MFMA, bf16 output, full-row prefetch) ----
    gemm_mfma_kernel<<<(n + 63) / 64, 256, 0, stream>>>(feat, Wf, bias, B0, n);

    // ---- 3 SpMM hops: B0 -> B1 -> B0 -> out(fp32) ----
    const int hblocks = (n + 15) / 16;
    spmm_csr_kernel<false><<<hblocks, 256, 0, stream>>>(rowptr, spack, B0, B1, n);
    spmm_csr_kernel<false><<<hblocks, 256, 0, stream>>>(rowptr, spack, B1, B0, n);
    spmm_csr_kernel<true><<<hblocks, 256, 0, stream>>>(rowptr, spack, B0, out, n);
}